// Round 4
// baseline (33.840 us; speedup 1.0000x reference)
//
#include <hip/hip_runtime.h>
#include <math.h>

// LogicConv2d, two-kernel form.
//
// prep (1 block): softmax(sel_a), softmax(sel_b), and collapse the 16-way
//   soft-logic mix to out = Cab*ab + Ca*a + Cb*b + C0. Packed into d_ws as
//   tab[81][24]: sa[9] sb[9] Cab Ca Cb C0 pad[2]  (96 B/record).
//
// main: block = 256 threads (4 waves) <-> 64 batches; lane <-> batch.
//   Wave w owns contiguous units [w*81/4, (w+1)*81/4) -> exactly 3 patches
//   -> 27 inputs hoisted to registers. Weights fetched via wave-uniform
//   scalar loads from d_ws (readfirstlane-forced). Single 20.7 KB LDS tile
//   is used for input staging AND output transpose (barrier between the
//   register hoist and the first overwrite).

#define NB      131072
#define NUNITS  81
#define BPB     64            // batches per block
#define THREADS 256
#define NBLK    (NB / BPB)    // 2048
#define REC     24            // floats per unit record
#define CHUNKS  1296          // BPB*81/4 float4 per tile

__global__ __launch_bounds__(256)
void logic_prep_kernel(const float* __restrict__ sa_logits,
                       const float* __restrict__ sb_logits,
                       const float* __restrict__ op_logits,
                       float* __restrict__ tab)
{
    const int tid = threadIdx.x;
    if (tid < 81) {
        const int u = tid;
        float v[9], m = -1e30f;
        #pragma unroll
        for (int i = 0; i < 9; ++i) { v[i] = sa_logits[u * 9 + i]; m = fmaxf(m, v[i]); }
        float s = 0.f;
        #pragma unroll
        for (int i = 0; i < 9; ++i) { v[i] = expf(v[i] - m); s += v[i]; }
        const float r = 1.f / s;
        #pragma unroll
        for (int i = 0; i < 9; ++i) tab[u * REC + i] = v[i] * r;
    } else if (tid < 162) {
        const int u = tid - 81;
        float v[9], m = -1e30f;
        #pragma unroll
        for (int i = 0; i < 9; ++i) { v[i] = sb_logits[u * 9 + i]; m = fmaxf(m, v[i]); }
        float s = 0.f;
        #pragma unroll
        for (int i = 0; i < 9; ++i) { v[i] = expf(v[i] - m); s += v[i]; }
        const float r = 1.f / s;
        #pragma unroll
        for (int i = 0; i < 9; ++i) tab[u * REC + 9 + i] = v[i] * r;
    } else if (tid < 243) {
        const int u = tid - 162;
        float v[16], m = -1e30f;
        #pragma unroll
        for (int i = 0; i < 16; ++i) { v[i] = op_logits[u * 16 + i]; m = fmaxf(m, v[i]); }
        float s = 0.f;
        #pragma unroll
        for (int i = 0; i < 16; ++i) { v[i] = expf(v[i] - m); s += v[i]; }
        const float r = 1.f / s;
        #pragma unroll
        for (int i = 0; i < 16; ++i) v[i] *= r;
        const float cab = v[1] - v[2] - v[4] - 2.f*v[6] - v[7] + v[8] + 2.f*v[9]
                        + v[11] + v[13] - v[14];
        const float ca  = v[2] + v[3] + v[6] + v[7] - v[8] - v[9] - v[12] - v[13];
        const float cb  = v[4] + v[5] + v[6] + v[7] - v[8] - v[9] - v[10] - v[11];
        const float c0  = v[8] + v[9] + v[10] + v[11] + v[12] + v[13] + v[14] + v[15];
        tab[u * REC + 18] = cab;
        tab[u * REC + 19] = ca;
        tab[u * REC + 20] = cb;
        tab[u * REC + 21] = c0;
    }
}

__global__ __launch_bounds__(THREADS, 4)
void logic_main_kernel(const float* __restrict__ x,
                       const float* __restrict__ tab,
                       float* __restrict__ out)
{
    __shared__ float s_tile[BPB * 81];    // 20736 B: input tile, then output tile

    const int tid  = threadIdx.x;
    const int lane = tid & 63;
    const int wave = tid >> 6;
    const size_t b0 = (size_t)blockIdx.x * BPB;

    // ---- stage input tile: coalesced float4 ----
    {
        const float4* gsrc = (const float4*)(x + b0 * 81);
        float4* s4 = (float4*)s_tile;
        #pragma unroll
        for (int k = 0; k < 6; ++k) {
            int j = tid + k * THREADS;
            if (j < CHUNKS) s4[j] = gsrc[j];
        }
    }
    __syncthreads();

    // ---- hoist this wave's 3 patches (27 inputs) into registers ----
    const int u0 = (wave * NUNITS) >> 2;        // 0,20,40,60
    const int u1 = ((wave + 1) * NUNITS) >> 2;  // 20,40,60,81
    const int p0 = u0 / 9;                      // first patch: 0,2,4,6
    const float* my_in = s_tile + lane * 81;    // stride 81 -> 2-way bank alias = free

    float in[3][9];
    #pragma unroll
    for (int pp = 0; pp < 3; ++pp) {
        const int p    = p0 + pp;
        const int base = (p / 3) * 27 + (p % 3) * 3;
        #pragma unroll
        for (int r = 0; r < 3; ++r) {
            in[pp][r*3+0] = my_in[base + r*9 + 0];
            in[pp][r*3+1] = my_in[base + r*9 + 1];
            in[pp][r*3+2] = my_in[base + r*9 + 2];
        }
    }

    // all waves must finish reading before any wave overwrites the tile
    __syncthreads();

    // ---- compute: u contiguous per wave, weights via scalar loads ----
    #pragma unroll
    for (int pp = 0; pp < 3; ++pp) {
        const int p  = p0 + pp;
        const int ua = (u0 > p * 9)     ? u0 : p * 9;
        const int ub = (u1 < p * 9 + 9) ? u1 : p * 9 + 9;
        for (int u = ua; u < ub; ++u) {
            const int uu = __builtin_amdgcn_readfirstlane(u);   // force SMEM path
            const float* __restrict__ wr = tab + (size_t)uu * REC;
            const float a = in[pp][0]*wr[0] + in[pp][1]*wr[1] + in[pp][2]*wr[2]
                          + in[pp][3]*wr[3] + in[pp][4]*wr[4] + in[pp][5]*wr[5]
                          + in[pp][6]*wr[6] + in[pp][7]*wr[7] + in[pp][8]*wr[8];
            const float b = in[pp][0]*wr[9]  + in[pp][1]*wr[10] + in[pp][2]*wr[11]
                          + in[pp][3]*wr[12] + in[pp][4]*wr[13] + in[pp][5]*wr[14]
                          + in[pp][6]*wr[15] + in[pp][7]*wr[16] + in[pp][8]*wr[17];
            s_tile[lane * 81 + u] = wr[21] + wr[19]*a + wr[20]*b + wr[18]*(a*b);
        }
    }

    __syncthreads();

    // ---- coalesced writeback ----
    {
        const float4* s4 = (const float4*)s_tile;
        float4* gdst = (float4*)(out + b0 * 81);
        #pragma unroll
        for (int k = 0; k < 6; ++k) {
            int j = tid + k * THREADS;
            if (j < CHUNKS) gdst[j] = s4[j];
        }
    }
}

extern "C" void kernel_launch(void* const* d_in, const int* in_sizes, int n_in,
                              void* d_out, int out_size, void* d_ws, size_t ws_size,
                              hipStream_t stream)
{
    const float* x  = (const float*)d_in[0];
    const float* sa = (const float*)d_in[1];
    const float* sb = (const float*)d_in[2];
    const float* op = (const float*)d_in[3];
    float* tab = (float*)d_ws;              // 81*24*4 = 7776 B
    float* outp = (float*)d_out;

    logic_prep_kernel<<<1, 256, 0, stream>>>(sa, sb, op, tab);
    logic_main_kernel<<<NBLK, THREADS, 0, stream>>>(x, tab, outp);
}

// Round 5
// 32.801 us; speedup vs baseline: 1.0317x; 1.0317x over previous
//
#include <hip/hip_runtime.h>
#include <math.h>

// LogicConv2d, two-kernel form, fully-unrolled compute.
//
// prep (1 block): softmax(sel_a), softmax(sel_b), collapse the 16-way mix to
//   out = Cab*ab + Ca*a + Cb*b + C0. tab[81][24] in d_ws:
//   sa[9] sb[9] Cab Ca Cb C0 pad[2] (96 B/record).
//
// main: block = 256 threads (4 waves) <-> 64 batches; lane <-> batch.
//   Compute uses waves 0..2 only: wave w owns units 27w..27w+26 == patch-row w
//   (uniform trip count 27 -> full unroll -> weight reads become batched
//   immediate-offset s_loads off a wave-uniform base). Wave w's LDS read-slice
//   equals its write-slice and slices are disjoint across waves -> no mid
//   barrier. Single 20.7 KB LDS tile for input staging AND output transpose.

#define NB      131072
#define NUNITS  81
#define BPB     64            // batches per block
#define THREADS 256
#define NBLK    (NB / BPB)    // 2048
#define REC     24            // floats per unit record
#define CHUNKS  1296          // BPB*81/4 float4 per tile

__global__ __launch_bounds__(256)
void logic_prep_kernel(const float* __restrict__ sa_logits,
                       const float* __restrict__ sb_logits,
                       const float* __restrict__ op_logits,
                       float* __restrict__ tab)
{
    const int tid = threadIdx.x;
    if (tid < 81) {
        const int u = tid;
        float v[9], m = -1e30f;
        #pragma unroll
        for (int i = 0; i < 9; ++i) { v[i] = sa_logits[u * 9 + i]; m = fmaxf(m, v[i]); }
        float s = 0.f;
        #pragma unroll
        for (int i = 0; i < 9; ++i) { v[i] = expf(v[i] - m); s += v[i]; }
        const float r = 1.f / s;
        #pragma unroll
        for (int i = 0; i < 9; ++i) tab[u * REC + i] = v[i] * r;
    } else if (tid < 162) {
        const int u = tid - 81;
        float v[9], m = -1e30f;
        #pragma unroll
        for (int i = 0; i < 9; ++i) { v[i] = sb_logits[u * 9 + i]; m = fmaxf(m, v[i]); }
        float s = 0.f;
        #pragma unroll
        for (int i = 0; i < 9; ++i) { v[i] = expf(v[i] - m); s += v[i]; }
        const float r = 1.f / s;
        #pragma unroll
        for (int i = 0; i < 9; ++i) tab[u * REC + 9 + i] = v[i] * r;
    } else if (tid < 243) {
        const int u = tid - 162;
        float v[16], m = -1e30f;
        #pragma unroll
        for (int i = 0; i < 16; ++i) { v[i] = op_logits[u * 16 + i]; m = fmaxf(m, v[i]); }
        float s = 0.f;
        #pragma unroll
        for (int i = 0; i < 16; ++i) { v[i] = expf(v[i] - m); s += v[i]; }
        const float r = 1.f / s;
        #pragma unroll
        for (int i = 0; i < 16; ++i) v[i] *= r;
        const float cab = v[1] - v[2] - v[4] - 2.f*v[6] - v[7] + v[8] + 2.f*v[9]
                        + v[11] + v[13] - v[14];
        const float ca  = v[2] + v[3] + v[6] + v[7] - v[8] - v[9] - v[12] - v[13];
        const float cb  = v[4] + v[5] + v[6] + v[7] - v[8] - v[9] - v[10] - v[11];
        const float c0  = v[8] + v[9] + v[10] + v[11] + v[12] + v[13] + v[14] + v[15];
        tab[u * REC + 18] = cab;
        tab[u * REC + 19] = ca;
        tab[u * REC + 20] = cb;
        tab[u * REC + 21] = c0;
    }
}

__global__ __launch_bounds__(THREADS)
void logic_main_kernel(const float* __restrict__ x,
                       const float* __restrict__ tab,
                       float* __restrict__ out)
{
    __shared__ float s_tile[BPB * 81];    // 20736 B: input tile, then output tile

    const int tid  = threadIdx.x;
    const int lane = tid & 63;
    const int wavei = __builtin_amdgcn_readfirstlane(tid >> 6);  // wave-uniform
    const size_t b0 = (size_t)blockIdx.x * BPB;

    // ---- stage input tile: coalesced float4 ----
    {
        const float4* gsrc = (const float4*)(x + b0 * 81);
        float4* s4 = (float4*)s_tile;
        #pragma unroll
        for (int k = 0; k < 6; ++k) {
            int j = tid + k * THREADS;
            if (j < CHUNKS) s4[j] = gsrc[j];
        }
    }
    __syncthreads();

    // ---- compute: wave w (w<3) owns units 27w..27w+26 (== patch-row w) ----
    // Read-slice == write-slice per wave, disjoint across waves: no barrier
    // needed between hoist and result writes.
    if (wavei < 3) {
        float* my = s_tile + lane * 81 + wavei * 27;  // this wave's 27-elem slice

        float in[27];                                  // img rows 3w..3w+2
        #pragma unroll
        for (int j = 0; j < 27; ++j) in[j] = my[j];

        const float* __restrict__ wt = tab + wavei * 27 * REC;  // uniform base

        #pragma unroll
        for (int j = 0; j < 27; ++j) {                 // unit u = 27*wavei + j
            const int q = j / 9;                       // patch col within row
            const float* __restrict__ wr = wt + j * REC;  // immediate offsets
            float a = 0.f, b = 0.f;
            #pragma unroll
            for (int i = 0; i < 9; ++i) {
                // img flat idx (local to slice) = q*3 + (i/3)*9 + i%3
                const float xi = in[q * 3 + (i / 3) * 9 + (i % 3)];
                a = fmaf(xi, wr[i],     a);
                b = fmaf(xi, wr[9 + i], b);
            }
            const float ab = a * b;
            my[j] = fmaf(wr[18], ab, fmaf(wr[19], a, fmaf(wr[20], b, wr[21])));
        }
    }

    __syncthreads();

    // ---- coalesced writeback ----
    {
        const float4* s4 = (const float4*)s_tile;
        float4* gdst = (float4*)(out + b0 * 81);
        #pragma unroll
        for (int k = 0; k < 6; ++k) {
            int j = tid + k * THREADS;
            if (j < CHUNKS) gdst[j] = s4[j];
        }
    }
}

extern "C" void kernel_launch(void* const* d_in, const int* in_sizes, int n_in,
                              void* d_out, int out_size, void* d_ws, size_t ws_size,
                              hipStream_t stream)
{
    const float* x  = (const float*)d_in[0];
    const float* sa = (const float*)d_in[1];
    const float* sb = (const float*)d_in[2];
    const float* op = (const float*)d_in[3];
    float* tab = (float*)d_ws;              // 81*24*4 = 7776 B
    float* outp = (float*)d_out;

    logic_prep_kernel<<<1, 256, 0, stream>>>(sa, sb, op, tab);
    logic_main_kernel<<<NBLK, THREADS, 0, stream>>>(x, tab, outp);
}